// Round 1
// baseline (827.947 us; speedup 1.0000x reference)
//
#include <hip/hip_runtime.h>
#include <hip/hip_bf16.h>

// Problem constants (reference: D=128, BC=64, BS=512, K=6, OV=128, B=8)
#define NB 8            // batches
#define LSEQ 32768      // BC*BS positions per batch
#define DCH 128         // channels
#define CS 256          // scan chunk size
#define NCHUNK 1024     // NB * LSEQ / CS
#define NBLK 512        // B*BC conv blocks
#define PH 520          // padded rows per block (2 front + 512 + pad, rounded)
#define SCALE_F 0.08838834764831845f

typedef __bf16 bf16x8 __attribute__((ext_vector_type(8)));
typedef float f32x4 __attribute__((ext_vector_type(4)));

__device__ __forceinline__ float bf2f(unsigned short u) {
    return __uint_as_float(((unsigned)u) << 16);
}
__device__ __forceinline__ unsigned short f2bf(float f) {
    unsigned u = __float_as_uint(f);
    u += 0x7fffu + ((u >> 16) & 1u);   // round-to-nearest-even
    return (unsigned short)(u >> 16);
}

// ---------------- Stage 1: logits = silu(x @ w_lw + b) + per-chunk max ----------------
__global__ __launch_bounds__(256) void k_logits(const float* __restrict__ x,
                                                const float* __restrict__ w_lw,
                                                const float* __restrict__ b_lw,
                                                float* __restrict__ logits,
                                                float* __restrict__ cmax) {
    int chunk = blockIdx.x;
    int t = threadIdx.x, wave = t >> 6, lane = t & 63;
    __shared__ float wmax_lds[4];
    float2 wl = *(const float2*)(w_lw + 2 * lane);
    float bb = b_lw[0];
    float wmax = -INFINITY;
    int p0 = chunk * CS;
    for (int i = 0; i < 64; i++) {
        int pos = p0 + wave * 64 + i;
        float2 xv = *(const float2*)(x + (size_t)pos * DCH + 2 * lane);
        float d = xv.x * wl.x + xv.y * wl.y;
        #pragma unroll
        for (int off = 32; off >= 1; off >>= 1) d += __shfl_xor(d, off, 64);
        float z = d + bb;
        float lg = z / (1.f + expf(-z));
        if (lane == 0) logits[pos] = lg;
        wmax = fmaxf(wmax, lg);
    }
    if (lane == 0) wmax_lds[wave] = wmax;
    __syncthreads();
    if (t == 0)
        cmax[chunk] = fmaxf(fmaxf(wmax_lds[0], wmax_lds[1]), fmaxf(wmax_lds[2], wmax_lds[3]));
}

// ---------------- Stage 2: exclusive prefix-max of chunk maxima (per batch) ----------------
__global__ void k_seed_max(const float* __restrict__ cmax, float* __restrict__ seedM) {
    int b = threadIdx.x;
    if (b < NB) {
        float run = -INFINITY;
        for (int c = 0; c < 128; c++) {
            seedM[b * 128 + c] = run;
            run = fmaxf(run, cmax[b * 128 + c]);
        }
    }
}

// ---------------- Stage 3: in-chunk cummax -> ex; chunk sums of ex and ex*x ----------------
__global__ __launch_bounds__(256) void k_chunk_sums(const float* __restrict__ x,
                                                    const float* __restrict__ logits,
                                                    const float* __restrict__ seedM,
                                                    float* __restrict__ ex,
                                                    float* __restrict__ S_ex,
                                                    float* __restrict__ S_exx) {
    int chunk = blockIdx.x, t = threadIdx.x;
    __shared__ float sc[CS];
    __shared__ float exl[CS];
    __shared__ float red[256];
    int p0 = chunk * CS;
    float lv = logits[p0 + t];
    sc[t] = lv;
    __syncthreads();
    // Hillis-Steele inclusive max-scan over 256
    for (int off = 1; off < CS; off <<= 1) {
        float v = sc[t];
        if (t >= off) v = fmaxf(v, sc[t - off]);
        __syncthreads();
        sc[t] = v;
        __syncthreads();
    }
    float pmax = fmaxf(sc[t], seedM[chunk]);
    float e = expf(lv - pmax);
    exl[t] = e;
    ex[p0 + t] = e;
    red[t] = e;
    __syncthreads();
    for (int off = 128; off > 0; off >>= 1) {
        if (t < off) red[t] += red[t + off];
        __syncthreads();
    }
    if (t == 0) S_ex[chunk] = red[0];
    // sum over chunk of ex[j]*x[j][c]  (two halves per channel)
    int c = t & 127, half = t >> 7;
    float acc = 0.f;
    const float* xp = x + (size_t)(p0 + half * 128) * DCH + c;
    for (int j = 0; j < 128; j++) acc += exl[half * 128 + j] * xp[j * DCH];
    red[t] = acc;
    __syncthreads();
    if (t < 128) S_exx[chunk * DCH + t] = red[t] + red[t + 128];
}

// ---------------- Stage 4: exclusive prefix sums of chunk aggregates ----------------
__global__ __launch_bounds__(128) void k_seed_sums(const float* __restrict__ S_ex,
                                                   const float* __restrict__ S_exx,
                                                   float* __restrict__ seed_ex,
                                                   float* __restrict__ seed_exx) {
    int b = blockIdx.x, t = threadIdx.x;
    float accv = 0.f, accs = 0.f;
    for (int c = 0; c < 128; c++) {
        int ch = b * 128 + c;
        if (t == 0) seed_ex[ch] = accs;
        accs += S_ex[ch];
        seed_exx[ch * DCH + t] = accv;
        accv += S_exx[ch * DCH + t];
    }
}

// ---------------- zero the halo rows of P ----------------
__global__ __launch_bounds__(256) void k_zero_pad(unsigned short* __restrict__ P) {
    int n = blockIdx.x, t = threadIdx.x;
    for (int i = t; i < 1024; i += 256) {
        int rr = i >> 7;                       // 0..7
        int row = (rr < 2) ? rr : 512 + rr;    // rows 0,1,514..519
        P[(n * PH + row) * DCH + (i & 127)] = 0;
    }
}

// ---------------- Stage 5: apply scan -> prefix_x, write bf16 padded P ----------------
__global__ __launch_bounds__(128) void k_apply(const float* __restrict__ x,
                                               const float* __restrict__ ex,
                                               const float* __restrict__ seed_ex,
                                               const float* __restrict__ seed_exx,
                                               unsigned short* __restrict__ P) {
    int chunk = blockIdx.x, t = threadIdx.x;   // 128 threads
    int b = chunk >> 7, cb = chunk & 127;
    __shared__ float exl[CS];
    exl[t] = ex[chunk * CS + t];
    exl[t + 128] = ex[chunk * CS + 128 + t];
    __syncthreads();
    float acc_exx = seed_exx[chunk * DCH + t];
    float acc_ex = seed_ex[chunk];
    int pib0 = cb * CS;
    for (int j = 0; j < CS; j++) {
        int pos = chunk * CS + j;
        float e = exl[j];
        acc_ex += e;
        float xv = x[(size_t)pos * DCH + t];
        acc_exx += e * xv;
        float val = acc_exx / acc_ex + xv;
        int pib = pib0 + j;
        int n = b * 64 + (pib >> 9);
        int row = (pib & 511) + 2;
        P[(n * PH + row) * DCH + t] = f2bf(val);
    }
}

// ---------------- weight repack: W2t[o][kn*128+i] = conv_w[o][i][kn], bf16 ----------------
__global__ __launch_bounds__(256) void k_w2t(const float* __restrict__ conv_w,
                                             unsigned short* __restrict__ W2t) {
    int idx = blockIdx.x * 256 + threadIdx.x;  // 128*768 = 98304
    if (idx < 128 * 768) {
        int o = idx / 768, kk = idx % 768;
        int kn = kk >> 7, i = kk & 127;
        W2t[idx] = f2bf(conv_w[(o * 128 + i) * 6 + kn]);
    }
}

// ---------------- Stage 6: conv as bf16 MFMA GEMM (128x128 tile, K=768) ----------------
__global__ __launch_bounds__(256) void k_conv(const unsigned short* __restrict__ P,
                                              const unsigned short* __restrict__ W2t,
                                              const float* __restrict__ conv_b,
                                              unsigned short* __restrict__ convout) {
    int n = blockIdx.x >> 2;
    int h0 = (blockIdx.x & 3) * 128;
    __shared__ __align__(16) unsigned short Alds[128 * 72];  // +8 pad vs bank conflicts
    __shared__ __align__(16) unsigned short Blds[128 * 72];
    int t = threadIdx.x;
    int wave = t >> 6, lane = t & 63;
    f32x4 acc[4][4] = {};
    const unsigned short* Pn = P + (size_t)n * PH * DCH;
    int wm = (wave >> 1) * 64, wn = (wave & 1) * 64;

    for (int kt = 0; kt < 12; ++kt) {
        int K0 = kt * 64;
        int kn = K0 >> 7;      // neighbor offset 0..5
        int c0 = K0 & 127;     // channel slice 0 or 64
        uint4 av[4], bv[4];
        #pragma unroll
        for (int i = 0; i < 4; ++i) {
            int ch = t + i * 256;
            int r = ch >> 3, off = ch & 7;
            av[i] = *(const uint4*)(Pn + (h0 + r + kn) * DCH + c0 + off * 8);
            bv[i] = *(const uint4*)(W2t + r * 768 + K0 + off * 8);
        }
        __syncthreads();   // previous iteration's LDS reads done
        #pragma unroll
        for (int i = 0; i < 4; ++i) {
            int ch = t + i * 256;
            int r = ch >> 3, off = ch & 7;
            *(uint4*)(Alds + r * 72 + off * 8) = av[i];
            *(uint4*)(Blds + r * 72 + off * 8) = bv[i];
        }
        __syncthreads();
        #pragma unroll
        for (int ks = 0; ks < 2; ++ks) {
            bf16x8 af[4], bfr[4];
            #pragma unroll
            for (int mi = 0; mi < 4; ++mi)
                af[mi] = *(const bf16x8*)(const void*)(Alds + (wm + mi * 16 + (lane & 15)) * 72 +
                                                      ks * 32 + (lane >> 4) * 8);
            #pragma unroll
            for (int ni = 0; ni < 4; ++ni)
                bfr[ni] = *(const bf16x8*)(const void*)(Blds + (wn + ni * 16 + (lane & 15)) * 72 +
                                                        ks * 32 + (lane >> 4) * 8);
            #pragma unroll
            for (int mi = 0; mi < 4; ++mi)
                #pragma unroll
                for (int ni = 0; ni < 4; ++ni)
                    acc[mi][ni] = __builtin_amdgcn_mfma_f32_16x16x32_bf16(af[mi], bfr[ni],
                                                                          acc[mi][ni], 0, 0, 0);
        }
    }
    // epilogue: C/D layout col=lane&15, row=(lane>>4)*4+reg  [m89-verified]
    #pragma unroll
    for (int mi = 0; mi < 4; ++mi)
        #pragma unroll
        for (int ni = 0; ni < 4; ++ni)
            #pragma unroll
            for (int r = 0; r < 4; ++r) {
                int row = wm + mi * 16 + (lane >> 4) * 4 + r;
                int col = wn + ni * 16 + (lane & 15);
                float v = acc[mi][ni][r] + conv_b[col];
                convout[(size_t)(n * 512 + h0 + row) * DCH + col] = f2bf(v);
            }
}

// ---------------- Stage 7: block_repr = max over h ----------------
__global__ __launch_bounds__(256) void k_repr(const unsigned short* __restrict__ convout,
                                              float* __restrict__ block_repr) {
    int n = blockIdx.x, t = threadIdx.x;
    __shared__ float red[256];
    int o = t & 127, half = t >> 7;
    float m = -INFINITY;
    for (int h = half * 256; h < half * 256 + 256; h++)
        m = fmaxf(m, bf2f(convout[(size_t)(n * 512 + h) * DCH + o]));
    red[t] = m;
    __syncthreads();
    if (t < 128) block_repr[n * DCH + t] = fmaxf(red[t], red[t + 128]);
}

// ---------------- Stage 8: a_s = attn(block_repr, conv, conv) ----------------
__global__ __launch_bounds__(256) void k_as(const unsigned short* __restrict__ convout,
                                            const float* __restrict__ block_repr,
                                            float* __restrict__ a_s) {
    int n = blockIdx.x, t = threadIdx.x, wave = t >> 6, lane = t & 63;
    __shared__ float br[128];
    __shared__ float s[512];
    __shared__ float red[256];
    if (t < 128) br[t] = block_repr[n * DCH + t];
    __syncthreads();
    float b0 = br[2 * lane], b1 = br[2 * lane + 1];
    for (int i = 0; i < 128; i++) {
        int h = wave * 128 + i;
        unsigned v = *(const unsigned*)(convout + (size_t)(n * 512 + h) * DCH + 2 * lane);
        float d = bf2f(v & 0xffff) * b0 + bf2f(v >> 16) * b1;
        #pragma unroll
        for (int off = 32; off >= 1; off >>= 1) d += __shfl_xor(d, off, 64);
        if (lane == 0) s[h] = d * SCALE_F;
    }
    __syncthreads();
    float m = fmaxf(s[t], s[t + 256]);
    red[t] = m;
    __syncthreads();
    for (int off = 128; off > 0; off >>= 1) {
        if (t < off) red[t] = fmaxf(red[t], red[t + off]);
        __syncthreads();
    }
    float smax = red[0];
    __syncthreads();
    float e0 = expf(s[t] - smax), e1 = expf(s[t + 256] - smax);
    red[t] = e0 + e1;
    __syncthreads();
    for (int off = 128; off > 0; off >>= 1) {
        if (t < off) red[t] += red[t + off];
        __syncthreads();
    }
    float inv = 1.f / red[0];
    __syncthreads();
    s[t] = e0 * inv;
    s[t + 256] = e1 * inv;
    __syncthreads();
    int o = t & 127, half = t >> 7;
    float acc = 0.f;
    for (int h = half * 256; h < half * 256 + 256; h++)
        acc += s[h] * bf2f(convout[(size_t)(n * 512 + h) * DCH + o]);
    red[t] = acc;
    __syncthreads();
    if (t < 128) a_s[n * DCH + t] = red[t] + red[t + 128];
}

// ---------------- Stage 9: a_o = attn(block_repr, xbo, xbo) over OV=128 window ----------------
__global__ __launch_bounds__(128) void k_ao(const unsigned short* __restrict__ P,
                                            const float* __restrict__ block_repr,
                                            float* __restrict__ a_o) {
    int n = blockIdx.x, t = threadIdx.x, wave = t >> 6, lane = t & 63;
    int b = n >> 6, c = n & 63;
    __shared__ float br[128];
    __shared__ float s[128];
    __shared__ int rb[128];
    __shared__ float red[128];
    br[t] = block_repr[n * DCH + t];
    {
        int pib = (c + 1) * 512 - 64 + t;       // window straddling block end
        pib = min(pib, LSEQ - 1);               // edge-clamp at sequence end
        int n2 = b * 64 + (pib >> 9);
        int row = (pib & 511) + 2;
        rb[t] = (n2 * PH + row) * DCH;
    }
    __syncthreads();
    float b0 = br[2 * lane], b1 = br[2 * lane + 1];
    for (int i = 0; i < 64; i++) {
        int q = wave * 64 + i;
        unsigned v = *(const unsigned*)(P + rb[q] + 2 * lane);
        float d = bf2f(v & 0xffff) * b0 + bf2f(v >> 16) * b1;
        #pragma unroll
        for (int off = 32; off >= 1; off >>= 1) d += __shfl_xor(d, off, 64);
        if (lane == 0) s[q] = d * SCALE_F;
    }
    __syncthreads();
    red[t] = s[t];
    __syncthreads();
    for (int off = 64; off > 0; off >>= 1) {
        if (t < off) red[t] = fmaxf(red[t], red[t + off]);
        __syncthreads();
    }
    float smax = red[0];
    __syncthreads();
    float e = expf(s[t] - smax);
    red[t] = e;
    __syncthreads();
    for (int off = 64; off > 0; off >>= 1) {
        if (t < off) red[t] += red[t + off];
        __syncthreads();
    }
    float inv = 1.f / red[0];
    __syncthreads();
    s[t] = e * inv;
    __syncthreads();
    float acc = 0.f;
    for (int q = 0; q < 128; q++) acc += s[q] * bf2f(P[rb[q] + t]);
    a_o[n * DCH + t] = acc;
}

// ---------------- Stage 10: out = concat(a_s,a_o,br) @ fusion_w + fusion_b (x2 copies) ----------------
__global__ __launch_bounds__(128) void k_fusion(const float* __restrict__ a_s,
                                                const float* __restrict__ a_o,
                                                const float* __restrict__ block_repr,
                                                const float* __restrict__ fusion_w,
                                                const float* __restrict__ fusion_b,
                                                float* __restrict__ out) {
    int n = blockIdx.x, t = threadIdx.x;
    __shared__ float fu[384];
    fu[t] = a_s[n * DCH + t];
    fu[128 + t] = a_o[n * DCH + t];
    fu[256 + t] = block_repr[n * DCH + t];
    __syncthreads();
    float acc = fusion_b[t];
    for (int j = 0; j < 384; j++) acc += fu[j] * fusion_w[j * DCH + t];
    out[n * DCH + t] = acc;
    out[NB * 64 * DCH + n * DCH + t] = acc;   // second tuple element (out, out)
}

extern "C" void kernel_launch(void* const* d_in, const int* in_sizes, int n_in,
                              void* d_out, int out_size, void* d_ws, size_t ws_size,
                              hipStream_t stream) {
    const float* x        = (const float*)d_in[0];
    const float* w_lw     = (const float*)d_in[1];
    const float* b_lw     = (const float*)d_in[2];
    const float* conv_w   = (const float*)d_in[3];
    const float* conv_b   = (const float*)d_in[4];
    const float* fusion_w = (const float*)d_in[5];
    const float* fusion_b = (const float*)d_in[6];
    float* out = (float*)d_out;

    char* ws = (char*)d_ws;
    size_t off = 0;
    auto alloc = [&](size_t bytes) { char* p = ws + off; off += (bytes + 255) & ~(size_t)255; return p; };
    float* logits     = (float*)alloc(NB * LSEQ * 4);
    float* exbuf      = (float*)alloc(NB * LSEQ * 4);
    float* cmax       = (float*)alloc(NCHUNK * 4);
    float* seedM      = (float*)alloc(NCHUNK * 4);
    float* S_ex       = (float*)alloc(NCHUNK * 4);
    float* seed_ex    = (float*)alloc(NCHUNK * 4);
    float* S_exx      = (float*)alloc(NCHUNK * DCH * 4);
    float* seed_exx   = (float*)alloc(NCHUNK * DCH * 4);
    float* block_repr = (float*)alloc(NBLK * DCH * 4);
    float* a_s        = (float*)alloc(NBLK * DCH * 4);
    float* a_o        = (float*)alloc(NBLK * DCH * 4);
    unsigned short* W2t     = (unsigned short*)alloc(128 * 768 * 2);
    unsigned short* P       = (unsigned short*)alloc((size_t)NBLK * PH * DCH * 2);
    unsigned short* convout = (unsigned short*)alloc((size_t)NBLK * 512 * DCH * 2);

    k_zero_pad<<<NBLK, 256, 0, stream>>>(P);
    k_w2t<<<384, 256, 0, stream>>>(conv_w, W2t);
    k_logits<<<NCHUNK, 256, 0, stream>>>(x, w_lw, b_lw, logits, cmax);
    k_seed_max<<<1, 64, 0, stream>>>(cmax, seedM);
    k_chunk_sums<<<NCHUNK, 256, 0, stream>>>(x, logits, seedM, exbuf, S_ex, S_exx);
    k_seed_sums<<<NB, 128, 0, stream>>>(S_ex, S_exx, seed_ex, seed_exx);
    k_apply<<<NCHUNK, 128, 0, stream>>>(x, exbuf, seed_ex, seed_exx, P);
    k_conv<<<NBLK * 4, 256, 0, stream>>>(P, W2t, conv_b, convout);
    k_repr<<<NBLK, 256, 0, stream>>>(convout, block_repr);
    k_as<<<NBLK, 256, 0, stream>>>(convout, block_repr, a_s);
    k_ao<<<NBLK, 128, 0, stream>>>(P, block_repr, a_o);
    k_fusion<<<NBLK, 128, 0, stream>>>(a_s, a_o, block_repr, fusion_w, fusion_b, out);
}

// Round 2
// 762.994 us; speedup vs baseline: 1.0851x; 1.0851x over previous
//
#include <hip/hip_runtime.h>
#include <hip/hip_bf16.h>

// Problem constants (reference: D=128, BC=64, BS=512, K=6, OV=128, B=8)
#define NB 8            // batches
#define LSEQ 32768      // BC*BS positions per batch
#define DCH 128         // channels
#define CS 256          // scan chunk size
#define NCHUNK 1024     // NB * LSEQ / CS
#define NBLK 512        // B*BC conv blocks
#define PH 520          // padded rows per block (2 front + 512 + pad, rounded)
#define SCALE_F 0.08838834764831845f

typedef __bf16 bf16x8 __attribute__((ext_vector_type(8)));
typedef float f32x4 __attribute__((ext_vector_type(4)));

__device__ __forceinline__ float bf2f(unsigned short u) {
    return __uint_as_float(((unsigned)u) << 16);
}
__device__ __forceinline__ unsigned short f2bf(float f) {
    unsigned u = __float_as_uint(f);
    u += 0x7fffu + ((u >> 16) & 1u);   // round-to-nearest-even
    return (unsigned short)(u >> 16);
}

// ---------------- Stage 1: logits = silu(x @ w_lw + b) + per-chunk max ----------------
__global__ __launch_bounds__(256) void k_logits(const float* __restrict__ x,
                                                const float* __restrict__ w_lw,
                                                const float* __restrict__ b_lw,
                                                float* __restrict__ logits,
                                                float* __restrict__ cmax) {
    int chunk = blockIdx.x;
    int t = threadIdx.x, wave = t >> 6, lane = t & 63;
    __shared__ float wmax_lds[4];
    float2 wl = *(const float2*)(w_lw + 2 * lane);
    float bb = b_lw[0];
    float wmax = -INFINITY;
    int p0 = chunk * CS;
    for (int i = 0; i < 64; i++) {
        int pos = p0 + wave * 64 + i;
        float2 xv = *(const float2*)(x + (size_t)pos * DCH + 2 * lane);
        float d = xv.x * wl.x + xv.y * wl.y;
        #pragma unroll
        for (int off = 32; off >= 1; off >>= 1) d += __shfl_xor(d, off, 64);
        float z = d + bb;
        float lg = z / (1.f + expf(-z));
        if (lane == 0) logits[pos] = lg;
        wmax = fmaxf(wmax, lg);
    }
    if (lane == 0) wmax_lds[wave] = wmax;
    __syncthreads();
    if (t == 0)
        cmax[chunk] = fmaxf(fmaxf(wmax_lds[0], wmax_lds[1]), fmaxf(wmax_lds[2], wmax_lds[3]));
}

// ---------------- Stage 2: exclusive prefix-max of chunk maxima (per batch) ----------------
__global__ void k_seed_max(const float* __restrict__ cmax, float* __restrict__ seedM) {
    int b = threadIdx.x;
    if (b < NB) {
        float run = -INFINITY;
        for (int c = 0; c < 128; c++) {
            seedM[b * 128 + c] = run;
            run = fmaxf(run, cmax[b * 128 + c]);
        }
    }
}

// ---------------- Stage 3: in-chunk cummax -> ex; chunk sums of ex and ex*x ----------------
__global__ __launch_bounds__(256) void k_chunk_sums(const float* __restrict__ x,
                                                    const float* __restrict__ logits,
                                                    const float* __restrict__ seedM,
                                                    float* __restrict__ ex,
                                                    float* __restrict__ S_ex,
                                                    float* __restrict__ S_exx) {
    int chunk = blockIdx.x, t = threadIdx.x;
    __shared__ float sc[CS];
    __shared__ float exl[CS];
    __shared__ float red[256];
    int p0 = chunk * CS;
    float lv = logits[p0 + t];
    sc[t] = lv;
    __syncthreads();
    // Hillis-Steele inclusive max-scan over 256
    for (int off = 1; off < CS; off <<= 1) {
        float v = sc[t];
        if (t >= off) v = fmaxf(v, sc[t - off]);
        __syncthreads();
        sc[t] = v;
        __syncthreads();
    }
    float pmax = fmaxf(sc[t], seedM[chunk]);
    float e = expf(lv - pmax);
    exl[t] = e;
    ex[p0 + t] = e;
    red[t] = e;
    __syncthreads();
    for (int off = 128; off > 0; off >>= 1) {
        if (t < off) red[t] += red[t + off];
        __syncthreads();
    }
    if (t == 0) S_ex[chunk] = red[0];
    // sum over chunk of ex[j]*x[j][c]  (two halves per channel)
    int c = t & 127, half = t >> 7;
    float acc = 0.f;
    const float* xp = x + (size_t)(p0 + half * 128) * DCH + c;
    for (int j = 0; j < 128; j++) acc += exl[half * 128 + j] * xp[j * DCH];
    red[t] = acc;
    __syncthreads();
    if (t < 128) S_exx[chunk * DCH + t] = red[t] + red[t + 128];
}

// ---------------- Stage 4: exclusive prefix sums of chunk aggregates ----------------
__global__ __launch_bounds__(128) void k_seed_sums(const float* __restrict__ S_ex,
                                                   const float* __restrict__ S_exx,
                                                   float* __restrict__ seed_ex,
                                                   float* __restrict__ seed_exx) {
    int b = blockIdx.x, t = threadIdx.x;
    float accv = 0.f, accs = 0.f;
    for (int c = 0; c < 128; c++) {
        int ch = b * 128 + c;
        if (t == 0) seed_ex[ch] = accs;
        accs += S_ex[ch];
        seed_exx[ch * DCH + t] = accv;
        accv += S_exx[ch * DCH + t];
    }
}

// ---------------- zero the halo rows of P ----------------
__global__ __launch_bounds__(256) void k_zero_pad(unsigned short* __restrict__ P) {
    int n = blockIdx.x, t = threadIdx.x;
    for (int i = t; i < 1024; i += 256) {
        int rr = i >> 7;                       // 0..7
        int row = (rr < 2) ? rr : 512 + rr;    // rows 0,1,514..519
        P[(n * PH + row) * DCH + (i & 127)] = 0;
    }
}

// ---------------- Stage 5: apply scan -> prefix_x, write bf16 padded P ----------------
__global__ __launch_bounds__(128) void k_apply(const float* __restrict__ x,
                                               const float* __restrict__ ex,
                                               const float* __restrict__ seed_ex,
                                               const float* __restrict__ seed_exx,
                                               unsigned short* __restrict__ P) {
    int chunk = blockIdx.x, t = threadIdx.x;   // 128 threads
    int b = chunk >> 7, cb = chunk & 127;
    __shared__ float exl[CS];
    exl[t] = ex[chunk * CS + t];
    exl[t + 128] = ex[chunk * CS + 128 + t];
    __syncthreads();
    float acc_exx = seed_exx[chunk * DCH + t];
    float acc_ex = seed_ex[chunk];
    int pib0 = cb * CS;
    for (int j = 0; j < CS; j++) {
        int pos = chunk * CS + j;
        float e = exl[j];
        acc_ex += e;
        float xv = x[(size_t)pos * DCH + t];
        acc_exx += e * xv;
        float val = acc_exx / acc_ex + xv;
        int pib = pib0 + j;
        int n = b * 64 + (pib >> 9);
        int row = (pib & 511) + 2;
        P[(n * PH + row) * DCH + t] = f2bf(val);
    }
}

// ---------------- weight repack: W2t[o][kn*128+i] = conv_w[o][i][kn], bf16 ----------------
__global__ __launch_bounds__(256) void k_w2t(const float* __restrict__ conv_w,
                                             unsigned short* __restrict__ W2t) {
    int idx = blockIdx.x * 256 + threadIdx.x;  // 128*768 = 98304
    if (idx < 128 * 768) {
        int o = idx / 768, kk = idx % 768;
        int kn = kk >> 7, i = kk & 127;
        W2t[idx] = f2bf(conv_w[(o * 128 + i) * 6 + kn]);
    }
}

// ---------------- Stage 6: conv as bf16 MFMA GEMM (128x128 tile, K=768) ----------------
// LDS A/B stride 72 ushorts (conflict-free b128); C-stage stride 136 ushorts.
__global__ __launch_bounds__(256) void k_conv(const unsigned short* __restrict__ P,
                                              const unsigned short* __restrict__ W2t,
                                              const float* __restrict__ conv_b,
                                              unsigned short* __restrict__ convout) {
    int n = blockIdx.x >> 2;
    int h0 = (blockIdx.x & 3) * 128;
    __shared__ __align__(16) unsigned short lds[2 * 128 * 72];  // 36,864 B
    unsigned short* Alds = lds;
    unsigned short* Blds = lds + 128 * 72;
    unsigned short* Clds = lds;                 // reused for C-stage (needs 128*136 <= 2*128*72)
    int t = threadIdx.x;
    int wave = t >> 6, lane = t & 63;
    f32x4 acc[4][4] = {};
    const unsigned short* Pn = P + (size_t)n * PH * DCH;
    int wm = (wave >> 1) * 64, wn = (wave & 1) * 64;

    for (int kt = 0; kt < 12; ++kt) {
        int K0 = kt * 64;
        int kn = K0 >> 7;      // neighbor offset 0..5
        int c0 = K0 & 127;     // channel slice 0 or 64
        uint4 av[4], bv[4];
        #pragma unroll
        for (int i = 0; i < 4; ++i) {
            int ch = t + i * 256;
            int r = ch >> 3, off = ch & 7;
            av[i] = *(const uint4*)(Pn + (h0 + r + kn) * DCH + c0 + off * 8);
            bv[i] = *(const uint4*)(W2t + r * 768 + K0 + off * 8);
        }
        __syncthreads();   // previous iteration's LDS reads done
        #pragma unroll
        for (int i = 0; i < 4; ++i) {
            int ch = t + i * 256;
            int r = ch >> 3, off = ch & 7;
            *(uint4*)(Alds + r * 72 + off * 8) = av[i];
            *(uint4*)(Blds + r * 72 + off * 8) = bv[i];
        }
        __syncthreads();
        #pragma unroll
        for (int ks = 0; ks < 2; ++ks) {
            bf16x8 af[4], bfr[4];
            #pragma unroll
            for (int mi = 0; mi < 4; ++mi)
                af[mi] = *(const bf16x8*)(const void*)(Alds + (wm + mi * 16 + (lane & 15)) * 72 +
                                                      ks * 32 + (lane >> 4) * 8);
            #pragma unroll
            for (int ni = 0; ni < 4; ++ni)
                bfr[ni] = *(const bf16x8*)(const void*)(Blds + (wn + ni * 16 + (lane & 15)) * 72 +
                                                        ks * 32 + (lane >> 4) * 8);
            #pragma unroll
            for (int mi = 0; mi < 4; ++mi)
                #pragma unroll
                for (int ni = 0; ni < 4; ++ni)
                    acc[mi][ni] = __builtin_amdgcn_mfma_f32_16x16x32_bf16(af[mi], bfr[ni],
                                                                          acc[mi][ni], 0, 0, 0);
        }
    }
    __syncthreads();   // all A/B LDS reads complete before Clds overwrite
    // C/D layout: col=lane&15, row=(lane>>4)*4+reg  [m89-verified]
    #pragma unroll
    for (int mi = 0; mi < 4; ++mi)
        #pragma unroll
        for (int ni = 0; ni < 4; ++ni) {
            int col = wn + ni * 16 + (lane & 15);
            float bias = conv_b[col];
            #pragma unroll
            for (int r = 0; r < 4; ++r) {
                int row = wm + mi * 16 + (lane >> 4) * 4 + r;
                Clds[row * 136 + col] = f2bf(acc[mi][ni][r] + bias);
            }
        }
    __syncthreads();
    // coalesced store: 2048 granules of 16 B
    size_t base = (size_t)(n * 512 + h0) * DCH;
    #pragma unroll
    for (int it = 0; it < 8; ++it) {
        int idx = it * 256 + t;
        int row = idx >> 4, g = idx & 15;
        uint4 v = *(const uint4*)(Clds + row * 136 + g * 8);
        *(uint4*)(convout + base + (size_t)row * DCH + g * 8) = v;
    }
}

// ---------------- Stage 7+8 fused: block_repr = max over h; a_s = attn(br, conv, conv) ----------------
__global__ __launch_bounds__(256) void k_as(const unsigned short* __restrict__ convout,
                                            float* __restrict__ block_repr,
                                            float* __restrict__ a_s) {
    int n = blockIdx.x, t = threadIdx.x, wave = t >> 6, lane = t & 63;
    __shared__ float br[128];
    __shared__ float s[512];
    __shared__ float red[256];
    // phase 0: column max over 512 rows -> block_repr
    {
        int o = t & 127, half = t >> 7;
        float m = -INFINITY;
        for (int h = half * 256; h < half * 256 + 256; h++)
            m = fmaxf(m, bf2f(convout[(size_t)(n * 512 + h) * DCH + o]));
        red[t] = m;
        __syncthreads();
        if (t < 128) {
            float bm = fmaxf(red[t], red[t + 128]);
            br[t] = bm;
            block_repr[n * DCH + t] = bm;
        }
        __syncthreads();
    }
    float b0 = br[2 * lane], b1 = br[2 * lane + 1];
    for (int i = 0; i < 128; i++) {
        int h = wave * 128 + i;
        unsigned v = *(const unsigned*)(convout + (size_t)(n * 512 + h) * DCH + 2 * lane);
        float d = bf2f(v & 0xffff) * b0 + bf2f(v >> 16) * b1;
        #pragma unroll
        for (int off = 32; off >= 1; off >>= 1) d += __shfl_xor(d, off, 64);
        if (lane == 0) s[h] = d * SCALE_F;
    }
    __syncthreads();
    float m = fmaxf(s[t], s[t + 256]);
    red[t] = m;
    __syncthreads();
    for (int off = 128; off > 0; off >>= 1) {
        if (t < off) red[t] = fmaxf(red[t], red[t + off]);
        __syncthreads();
    }
    float smax = red[0];
    __syncthreads();
    float e0 = expf(s[t] - smax), e1 = expf(s[t + 256] - smax);
    red[t] = e0 + e1;
    __syncthreads();
    for (int off = 128; off > 0; off >>= 1) {
        if (t < off) red[t] += red[t + off];
        __syncthreads();
    }
    float inv = 1.f / red[0];
    __syncthreads();
    s[t] = e0 * inv;
    s[t + 256] = e1 * inv;
    __syncthreads();
    int o = t & 127, half = t >> 7;
    float acc = 0.f;
    for (int h = half * 256; h < half * 256 + 256; h++)
        acc += s[h] * bf2f(convout[(size_t)(n * 512 + h) * DCH + o]);
    red[t] = acc;
    __syncthreads();
    if (t < 128) a_s[n * DCH + t] = red[t] + red[t + 128];
}

// ---------------- Stage 9: a_o = attn(block_repr, xbo, xbo) over OV=128 window ----------------
__global__ __launch_bounds__(128) void k_ao(const unsigned short* __restrict__ P,
                                            const float* __restrict__ block_repr,
                                            float* __restrict__ a_o) {
    int n = blockIdx.x, t = threadIdx.x, wave = t >> 6, lane = t & 63;
    int b = n >> 6, c = n & 63;
    __shared__ float br[128];
    __shared__ float s[128];
    __shared__ int rb[128];
    __shared__ float red[128];
    br[t] = block_repr[n * DCH + t];
    {
        int pib = (c + 1) * 512 - 64 + t;       // window straddling block end
        pib = min(pib, LSEQ - 1);               // edge-clamp at sequence end
        int n2 = b * 64 + (pib >> 9);
        int row = (pib & 511) + 2;
        rb[t] = (n2 * PH + row) * DCH;
    }
    __syncthreads();
    float b0 = br[2 * lane], b1 = br[2 * lane + 1];
    for (int i = 0; i < 64; i++) {
        int q = wave * 64 + i;
        unsigned v = *(const unsigned*)(P + rb[q] + 2 * lane);
        float d = bf2f(v & 0xffff) * b0 + bf2f(v >> 16) * b1;
        #pragma unroll
        for (int off = 32; off >= 1; off >>= 1) d += __shfl_xor(d, off, 64);
        if (lane == 0) s[q] = d * SCALE_F;
    }
    __syncthreads();
    red[t] = s[t];
    __syncthreads();
    for (int off = 64; off > 0; off >>= 1) {
        if (t < off) red[t] = fmaxf(red[t], red[t + off]);
        __syncthreads();
    }
    float smax = red[0];
    __syncthreads();
    float e = expf(s[t] - smax);
    red[t] = e;
    __syncthreads();
    for (int off = 64; off > 0; off >>= 1) {
        if (t < off) red[t] += red[t + off];
        __syncthreads();
    }
    float inv = 1.f / red[0];
    __syncthreads();
    s[t] = e * inv;
    __syncthreads();
    float acc = 0.f;
    for (int q = 0; q < 128; q++) acc += s[q] * bf2f(P[rb[q] + t]);
    a_o[n * DCH + t] = acc;
}

// ---------------- Stage 10: out = concat(a_s,a_o,br) @ fusion_w + fusion_b (x2 copies) ----------------
__global__ __launch_bounds__(128) void k_fusion(const float* __restrict__ a_s,
                                                const float* __restrict__ a_o,
                                                const float* __restrict__ block_repr,
                                                const float* __restrict__ fusion_w,
                                                const float* __restrict__ fusion_b,
                                                float* __restrict__ out) {
    int n = blockIdx.x, t = threadIdx.x;
    __shared__ float fu[384];
    fu[t] = a_s[n * DCH + t];
    fu[128 + t] = a_o[n * DCH + t];
    fu[256 + t] = block_repr[n * DCH + t];
    __syncthreads();
    float acc = fusion_b[t];
    for (int j = 0; j < 384; j++) acc += fu[j] * fusion_w[j * DCH + t];
    out[n * DCH + t] = acc;
    out[NB * 64 * DCH + n * DCH + t] = acc;   // second tuple element (out, out)
}

extern "C" void kernel_launch(void* const* d_in, const int* in_sizes, int n_in,
                              void* d_out, int out_size, void* d_ws, size_t ws_size,
                              hipStream_t stream) {
    const float* x        = (const float*)d_in[0];
    const float* w_lw     = (const float*)d_in[1];
    const float* b_lw     = (const float*)d_in[2];
    const float* conv_w   = (const float*)d_in[3];
    const float* conv_b   = (const float*)d_in[4];
    const float* fusion_w = (const float*)d_in[5];
    const float* fusion_b = (const float*)d_in[6];
    float* out = (float*)d_out;

    char* ws = (char*)d_ws;
    size_t off = 0;
    auto alloc = [&](size_t bytes) { char* p = ws + off; off += (bytes + 255) & ~(size_t)255; return p; };
    float* logits     = (float*)alloc(NB * LSEQ * 4);
    float* exbuf      = (float*)alloc(NB * LSEQ * 4);
    float* cmax       = (float*)alloc(NCHUNK * 4);
    float* seedM      = (float*)alloc(NCHUNK * 4);
    float* S_ex       = (float*)alloc(NCHUNK * 4);
    float* seed_ex    = (float*)alloc(NCHUNK * 4);
    float* S_exx      = (float*)alloc(NCHUNK * DCH * 4);
    float* seed_exx   = (float*)alloc(NCHUNK * DCH * 4);
    float* block_repr = (float*)alloc(NBLK * DCH * 4);
    float* a_s        = (float*)alloc(NBLK * DCH * 4);
    float* a_o        = (float*)alloc(NBLK * DCH * 4);
    unsigned short* W2t     = (unsigned short*)alloc(128 * 768 * 2);
    unsigned short* P       = (unsigned short*)alloc((size_t)NBLK * PH * DCH * 2);
    unsigned short* convout = (unsigned short*)alloc((size_t)NBLK * 512 * DCH * 2);

    k_zero_pad<<<NBLK, 256, 0, stream>>>(P);
    k_w2t<<<384, 256, 0, stream>>>(conv_w, W2t);
    k_logits<<<NCHUNK, 256, 0, stream>>>(x, w_lw, b_lw, logits, cmax);
    k_seed_max<<<1, 64, 0, stream>>>(cmax, seedM);
    k_chunk_sums<<<NCHUNK, 256, 0, stream>>>(x, logits, seedM, exbuf, S_ex, S_exx);
    k_seed_sums<<<NB, 128, 0, stream>>>(S_ex, S_exx, seed_ex, seed_exx);
    k_apply<<<NCHUNK, 128, 0, stream>>>(x, exbuf, seed_ex, seed_exx, P);
    k_conv<<<NBLK * 4, 256, 0, stream>>>(P, W2t, conv_b, convout);
    k_as<<<NBLK, 256, 0, stream>>>(convout, block_repr, a_s);
    k_ao<<<NBLK, 128, 0, stream>>>(P, block_repr, a_o);
    k_fusion<<<NBLK, 128, 0, stream>>>(a_s, a_o, block_repr, fusion_w, fusion_b, out);
}

// Round 3
// 599.070 us; speedup vs baseline: 1.3821x; 1.2736x over previous
//
#include <hip/hip_runtime.h>
#include <hip/hip_bf16.h>

// Problem constants (reference: D=128, BC=64, BS=512, K=6, OV=128, B=8)
#define NB 8            // batches
#define LSEQ 32768      // BC*BS positions per batch
#define DCH 128         // channels
#define CS 256          // scan chunk size
#define NCHUNK 1024     // NB * LSEQ / CS
#define NBLK 512        // B*BC conv blocks
#define PH 520          // padded rows per block (2 front + 512 + pad, rounded)
#define SCALE_F 0.08838834764831845f

typedef __bf16 bf16x8 __attribute__((ext_vector_type(8)));
typedef float f32x4 __attribute__((ext_vector_type(4)));

__device__ __forceinline__ float bf2f(unsigned short u) {
    return __uint_as_float(((unsigned)u) << 16);
}
__device__ __forceinline__ unsigned short f2bf(float f) {
    unsigned u = __float_as_uint(f);
    u += 0x7fffu + ((u >> 16) & 1u);   // round-to-nearest-even
    return (unsigned short)(u >> 16);
}

// async global->LDS DMA, 16 B per lane; LDS dest = wave-uniform base + lane*16
__device__ __forceinline__ void async_copy16(const void* gsrc, void* ldst) {
    __builtin_amdgcn_global_load_lds(
        (const __attribute__((address_space(1))) unsigned int*)gsrc,
        (__attribute__((address_space(3))) unsigned int*)ldst, 16, 0, 0);
}

// ---------------- Stage 1: logits = silu(x @ w_lw + b) + per-chunk max ----------------
__global__ __launch_bounds__(256) void k_logits(const float* __restrict__ x,
                                                const float* __restrict__ w_lw,
                                                const float* __restrict__ b_lw,
                                                float* __restrict__ logits,
                                                float* __restrict__ cmax) {
    int chunk = blockIdx.x;
    int t = threadIdx.x, wave = t >> 6, lane = t & 63;
    __shared__ float wmax_lds[4];
    float2 wl = *(const float2*)(w_lw + 2 * lane);
    float bb = b_lw[0];
    float wmax = -INFINITY;
    int p0 = chunk * CS;
    for (int i = 0; i < 64; i++) {
        int pos = p0 + wave * 64 + i;
        float2 xv = *(const float2*)(x + (size_t)pos * DCH + 2 * lane);
        float d = xv.x * wl.x + xv.y * wl.y;
        #pragma unroll
        for (int off = 32; off >= 1; off >>= 1) d += __shfl_xor(d, off, 64);
        float z = d + bb;
        float lg = z / (1.f + expf(-z));
        if (lane == 0) logits[pos] = lg;
        wmax = fmaxf(wmax, lg);
    }
    if (lane == 0) wmax_lds[wave] = wmax;
    __syncthreads();
    if (t == 0)
        cmax[chunk] = fmaxf(fmaxf(wmax_lds[0], wmax_lds[1]), fmaxf(wmax_lds[2], wmax_lds[3]));
}

// ---------------- Stage 2: exclusive prefix-max of chunk maxima (per batch) ----------------
__global__ void k_seed_max(const float* __restrict__ cmax, float* __restrict__ seedM) {
    int b = threadIdx.x;
    if (b < NB) {
        float run = -INFINITY;
        for (int c = 0; c < 128; c++) {
            seedM[b * 128 + c] = run;
            run = fmaxf(run, cmax[b * 128 + c]);
        }
    }
}

// ---------------- Stage 3: in-chunk cummax -> ex; chunk sums of ex and ex*x ----------------
__global__ __launch_bounds__(256) void k_chunk_sums(const float* __restrict__ x,
                                                    const float* __restrict__ logits,
                                                    const float* __restrict__ seedM,
                                                    float* __restrict__ ex,
                                                    float* __restrict__ S_ex,
                                                    float* __restrict__ S_exx) {
    int chunk = blockIdx.x, t = threadIdx.x;
    __shared__ float sc[CS];
    __shared__ float exl[CS];
    __shared__ float red[256];
    int p0 = chunk * CS;
    float lv = logits[p0 + t];
    sc[t] = lv;
    __syncthreads();
    // Hillis-Steele inclusive max-scan over 256
    for (int off = 1; off < CS; off <<= 1) {
        float v = sc[t];
        if (t >= off) v = fmaxf(v, sc[t - off]);
        __syncthreads();
        sc[t] = v;
        __syncthreads();
    }
    float pmax = fmaxf(sc[t], seedM[chunk]);
    float e = expf(lv - pmax);
    exl[t] = e;
    ex[p0 + t] = e;
    red[t] = e;
    __syncthreads();
    for (int off = 128; off > 0; off >>= 1) {
        if (t < off) red[t] += red[t + off];
        __syncthreads();
    }
    if (t == 0) S_ex[chunk] = red[0];
    // sum over chunk of ex[j]*x[j][c]  (two halves per channel)
    int c = t & 127, half = t >> 7;
    float acc = 0.f;
    const float* xp = x + (size_t)(p0 + half * 128) * DCH + c;
    for (int j = 0; j < 128; j++) acc += exl[half * 128 + j] * xp[j * DCH];
    red[t] = acc;
    __syncthreads();
    if (t < 128) S_exx[chunk * DCH + t] = red[t] + red[t + 128];
}

// ---------------- Stage 4: exclusive prefix sums of chunk aggregates ----------------
__global__ __launch_bounds__(128) void k_seed_sums(const float* __restrict__ S_ex,
                                                   const float* __restrict__ S_exx,
                                                   float* __restrict__ seed_ex,
                                                   float* __restrict__ seed_exx) {
    int b = blockIdx.x, t = threadIdx.x;
    float accv = 0.f, accs = 0.f;
    for (int c = 0; c < 128; c++) {
        int ch = b * 128 + c;
        if (t == 0) seed_ex[ch] = accs;
        accs += S_ex[ch];
        seed_exx[ch * DCH + t] = accv;
        accv += S_exx[ch * DCH + t];
    }
}

// ---------------- zero the halo rows of P ----------------
__global__ __launch_bounds__(256) void k_zero_pad(unsigned short* __restrict__ P) {
    int n = blockIdx.x, t = threadIdx.x;
    for (int i = t; i < 1024; i += 256) {
        int rr = i >> 7;                       // 0..7
        int row = (rr < 2) ? rr : 512 + rr;    // rows 0,1,514..519
        P[(n * PH + row) * DCH + (i & 127)] = 0;
    }
}

// ---------------- Stage 5: apply scan -> prefix_x, write bf16 padded P ----------------
__global__ __launch_bounds__(128) void k_apply(const float* __restrict__ x,
                                               const float* __restrict__ ex,
                                               const float* __restrict__ seed_ex,
                                               const float* __restrict__ seed_exx,
                                               unsigned short* __restrict__ P) {
    int chunk = blockIdx.x, t = threadIdx.x;   // 128 threads
    int b = chunk >> 7, cb = chunk & 127;
    __shared__ float exl[CS];
    exl[t] = ex[chunk * CS + t];
    exl[t + 128] = ex[chunk * CS + 128 + t];
    __syncthreads();
    float acc_exx = seed_exx[chunk * DCH + t];
    float acc_ex = seed_ex[chunk];
    int pib0 = cb * CS;
    for (int j = 0; j < CS; j++) {
        int pos = chunk * CS + j;
        float e = exl[j];
        acc_ex += e;
        float xv = x[(size_t)pos * DCH + t];
        acc_exx += e * xv;
        float val = acc_exx / acc_ex + xv;
        int pib = pib0 + j;
        int n = b * 64 + (pib >> 9);
        int row = (pib & 511) + 2;
        P[(n * PH + row) * DCH + t] = f2bf(val);
    }
}

// ---------------- weight repack: W2t[o][kn*128+i] = conv_w[o][i][kn], bf16 ----------------
__global__ __launch_bounds__(256) void k_w2t(const float* __restrict__ conv_w,
                                             unsigned short* __restrict__ W2t) {
    int idx = blockIdx.x * 256 + threadIdx.x;  // 128*768 = 98304
    if (idx < 128 * 768) {
        int o = idx / 768, kk = idx % 768;
        int kn = kk >> 7, i = kk & 127;
        W2t[idx] = f2bf(conv_w[(o * 128 + i) * 6 + kn]);
    }
}

// ---------------- Stage 6: conv as bf16 MFMA GEMM (128x128 tile, K=768) ----------------
// global_load_lds DMA staging, XOR-swizzled at the DMA *source* so the unpadded
// LDS image reads conflict-free. LDS: A[128][64] @0, B[128][64] @16KB (ushort),
// epilogue C-stage reuses the whole buffer at stride 136.
__global__ __launch_bounds__(256) void k_conv(const unsigned short* __restrict__ P,
                                              const unsigned short* __restrict__ W2t,
                                              const float* __restrict__ conv_b,
                                              unsigned short* __restrict__ convout) {
    int n = blockIdx.x >> 2;
    int h0 = (blockIdx.x & 3) * 128;
    __shared__ __align__(16) unsigned short lds[128 * 136];  // 34,816 B (>= 32 KB A+B)
    char* ldsA = (char*)lds;
    char* ldsB = (char*)lds + 16384;
    int t = threadIdx.x;
    int wave = t >> 6, lane = t & 63;
    f32x4 acc[4][4] = {};
    const unsigned short* Pn = P + (size_t)n * PH * DCH;
    int wm = (wave >> 1) * 64, wn = (wave & 1) * 64;
    int rdma = (lane >> 3);        // row-within-8 handled per DMA instr
    int cpos = lane & 7;           // LDS chunk position this lane fills

    for (int kt = 0; kt < 12; ++kt) {
        int kn = kt >> 1;              // neighbor offset 0..5
        int c0 = (kt & 1) * 64;        // channel slice 0 or 64
        __syncthreads();   // all waves done reading LDS for kt-1
        #pragma unroll
        for (int j = 0; j < 4; ++j) {
            int r = (wave * 4 + j) * 8 + rdma;          // LDS row 0..127
            int gr = h0 + kn + r;                       // global padded row
            int csrcA = cpos ^ (gr & 7);                // source-side swizzle
            async_copy16(Pn + (size_t)gr * DCH + c0 + csrcA * 8,
                         ldsA + (wave * 4 + j) * 1024 + lane * 16);
            int csrcB = cpos ^ (r & 7);
            async_copy16(W2t + (size_t)r * 768 + kt * 64 + csrcB * 8,
                         ldsB + (wave * 4 + j) * 1024 + lane * 16);
        }
        __syncthreads();   // drains vmcnt(0): DMA complete
        #pragma unroll
        for (int ks = 0; ks < 2; ++ks) {
            bf16x8 af[4], bfr[4];
            #pragma unroll
            for (int mi = 0; mi < 4; ++mi) {
                int rA = wm + mi * 16 + (lane & 15);
                int pA = (ks * 4 + (lane >> 4)) ^ ((kn + rA) & 7);
                af[mi] = *(const bf16x8*)(ldsA + rA * 128 + pA * 16);
            }
            #pragma unroll
            for (int ni = 0; ni < 4; ++ni) {
                int oB = wn + ni * 16 + (lane & 15);
                int pB = (ks * 4 + (lane >> 4)) ^ (oB & 7);
                bfr[ni] = *(const bf16x8*)(ldsB + oB * 128 + pB * 16);
            }
            #pragma unroll
            for (int mi = 0; mi < 4; ++mi)
                #pragma unroll
                for (int ni = 0; ni < 4; ++ni)
                    acc[mi][ni] = __builtin_amdgcn_mfma_f32_16x16x32_bf16(af[mi], bfr[ni],
                                                                          acc[mi][ni], 0, 0, 0);
        }
    }
    __syncthreads();   // all A/B LDS reads complete before C-stage overwrite
    // C/D layout: col=lane&15, row=(lane>>4)*4+reg  [m89-verified]
    #pragma unroll
    for (int mi = 0; mi < 4; ++mi)
        #pragma unroll
        for (int ni = 0; ni < 4; ++ni) {
            int col = wn + ni * 16 + (lane & 15);
            float bias = conv_b[col];
            #pragma unroll
            for (int r = 0; r < 4; ++r) {
                int row = wm + mi * 16 + (lane >> 4) * 4 + r;
                lds[row * 136 + col] = f2bf(acc[mi][ni][r] + bias);
            }
        }
    __syncthreads();
    // coalesced store: 2048 granules of 16 B
    size_t base = (size_t)(n * 512 + h0) * DCH;
    #pragma unroll
    for (int it = 0; it < 8; ++it) {
        int idx = it * 256 + t;
        int row = idx >> 4, g = idx & 15;
        uint4 v = *(const uint4*)(lds + row * 136 + g * 8);
        *(uint4*)(convout + base + (size_t)row * DCH + g * 8) = v;
    }
}

// ---------------- Stage 7+8 fused: block_repr = max over h; a_s = attn(br, conv, conv) ----------------
__global__ __launch_bounds__(256) void k_as(const unsigned short* __restrict__ convout,
                                            float* __restrict__ block_repr,
                                            float* __restrict__ a_s) {
    int n = blockIdx.x, t = threadIdx.x, wave = t >> 6, lane = t & 63;
    __shared__ float br[128];
    __shared__ float s[512];
    __shared__ float red[256];
    // phase 0: column max over 512 rows -> block_repr
    {
        int o = t & 127, half = t >> 7;
        float m = -INFINITY;
        for (int h = half * 256; h < half * 256 + 256; h++)
            m = fmaxf(m, bf2f(convout[(size_t)(n * 512 + h) * DCH + o]));
        red[t] = m;
        __syncthreads();
        if (t < 128) {
            float bm = fmaxf(red[t], red[t + 128]);
            br[t] = bm;
            block_repr[n * DCH + t] = bm;
        }
        __syncthreads();
    }
    float b0 = br[2 * lane], b1 = br[2 * lane + 1];
    for (int i = 0; i < 128; i++) {
        int h = wave * 128 + i;
        unsigned v = *(const unsigned*)(convout + (size_t)(n * 512 + h) * DCH + 2 * lane);
        float d = bf2f(v & 0xffff) * b0 + bf2f(v >> 16) * b1;
        #pragma unroll
        for (int off = 32; off >= 1; off >>= 1) d += __shfl_xor(d, off, 64);
        if (lane == 0) s[h] = d * SCALE_F;
    }
    __syncthreads();
    float m = fmaxf(s[t], s[t + 256]);
    red[t] = m;
    __syncthreads();
    for (int off = 128; off > 0; off >>= 1) {
        if (t < off) red[t] = fmaxf(red[t], red[t + off]);
        __syncthreads();
    }
    float smax = red[0];
    __syncthreads();
    float e0 = expf(s[t] - smax), e1 = expf(s[t + 256] - smax);
    red[t] = e0 + e1;
    __syncthreads();
    for (int off = 128; off > 0; off >>= 1) {
        if (t < off) red[t] += red[t + off];
        __syncthreads();
    }
    float inv = 1.f / red[0];
    __syncthreads();
    s[t] = e0 * inv;
    s[t + 256] = e1 * inv;
    __syncthreads();
    int o = t & 127, half = t >> 7;
    float acc = 0.f;
    for (int h = half * 256; h < half * 256 + 256; h++)
        acc += s[h] * bf2f(convout[(size_t)(n * 512 + h) * DCH + o]);
    red[t] = acc;
    __syncthreads();
    if (t < 128) a_s[n * DCH + t] = red[t] + red[t + 128];
}

// ---------------- Stage 9: a_o = attn(block_repr, xbo, xbo) over OV=128 window ----------------
__global__ __launch_bounds__(128) void k_ao(const unsigned short* __restrict__ P,
                                            const float* __restrict__ block_repr,
                                            float* __restrict__ a_o) {
    int n = blockIdx.x, t = threadIdx.x, wave = t >> 6, lane = t & 63;
    int b = n >> 6, c = n & 63;
    __shared__ float br[128];
    __shared__ float s[128];
    __shared__ int rb[128];
    __shared__ float red[128];
    br[t] = block_repr[n * DCH + t];
    {
        int pib = (c + 1) * 512 - 64 + t;       // window straddling block end
        pib = min(pib, LSEQ - 1);               // edge-clamp at sequence end
        int n2 = b * 64 + (pib >> 9);
        int row = (pib & 511) + 2;
        rb[t] = (n2 * PH + row) * DCH;
    }
    __syncthreads();
    float b0 = br[2 * lane], b1 = br[2 * lane + 1];
    for (int i = 0; i < 64; i++) {
        int q = wave * 64 + i;
        unsigned v = *(const unsigned*)(P + rb[q] + 2 * lane);
        float d = bf2f(v & 0xffff) * b0 + bf2f(v >> 16) * b1;
        #pragma unroll
        for (int off = 32; off >= 1; off >>= 1) d += __shfl_xor(d, off, 64);
        if (lane == 0) s[q] = d * SCALE_F;
    }
    __syncthreads();
    red[t] = s[t];
    __syncthreads();
    for (int off = 64; off > 0; off >>= 1) {
        if (t < off) red[t] = fmaxf(red[t], red[t + off]);
        __syncthreads();
    }
    float smax = red[0];
    __syncthreads();
    float e = expf(s[t] - smax);
    red[t] = e;
    __syncthreads();
    for (int off = 64; off > 0; off >>= 1) {
        if (t < off) red[t] += red[t + off];
        __syncthreads();
    }
    float inv = 1.f / red[0];
    __syncthreads();
    s[t] = e * inv;
    __syncthreads();
    float acc = 0.f;
    for (int q = 0; q < 128; q++) acc += s[q] * bf2f(P[rb[q] + t]);
    a_o[n * DCH + t] = acc;
}

// ---------------- Stage 10: out = concat(a_s,a_o,br) @ fusion_w + fusion_b (x2 copies) ----------------
__global__ __launch_bounds__(128) void k_fusion(const float* __restrict__ a_s,
                                                const float* __restrict__ a_o,
                                                const float* __restrict__ block_repr,
                                                const float* __restrict__ fusion_w,
                                                const float* __restrict__ fusion_b,
                                                float* __restrict__ out) {
    int n = blockIdx.x, t = threadIdx.x;
    __shared__ float fu[384];
    fu[t] = a_s[n * DCH + t];
    fu[128 + t] = a_o[n * DCH + t];
    fu[256 + t] = block_repr[n * DCH + t];
    __syncthreads();
    float acc = fusion_b[t];
    for (int j = 0; j < 384; j++) acc += fu[j] * fusion_w[j * DCH + t];
    out[n * DCH + t] = acc;
    out[NB * 64 * DCH + n * DCH + t] = acc;   // second tuple element (out, out)
}

extern "C" void kernel_launch(void* const* d_in, const int* in_sizes, int n_in,
                              void* d_out, int out_size, void* d_ws, size_t ws_size,
                              hipStream_t stream) {
    const float* x        = (const float*)d_in[0];
    const float* w_lw     = (const float*)d_in[1];
    const float* b_lw     = (const float*)d_in[2];
    const float* conv_w   = (const float*)d_in[3];
    const float* conv_b   = (const float*)d_in[4];
    const float* fusion_w = (const float*)d_in[5];
    const float* fusion_b = (const float*)d_in[6];
    float* out = (float*)d_out;

    char* ws = (char*)d_ws;
    size_t off = 0;
    auto alloc = [&](size_t bytes) { char* p = ws + off; off += (bytes + 255) & ~(size_t)255; return p; };
    float* logits     = (float*)alloc(NB * LSEQ * 4);
    float* exbuf      = (float*)alloc(NB * LSEQ * 4);
    float* cmax       = (float*)alloc(NCHUNK * 4);
    float* seedM      = (float*)alloc(NCHUNK * 4);
    float* S_ex       = (float*)alloc(NCHUNK * 4);
    float* seed_ex    = (float*)alloc(NCHUNK * 4);
    float* S_exx      = (float*)alloc(NCHUNK * DCH * 4);
    float* seed_exx   = (float*)alloc(NCHUNK * DCH * 4);
    float* block_repr = (float*)alloc(NBLK * DCH * 4);
    float* a_s        = (float*)alloc(NBLK * DCH * 4);
    float* a_o        = (float*)alloc(NBLK * DCH * 4);
    unsigned short* W2t     = (unsigned short*)alloc(128 * 768 * 2);
    unsigned short* P       = (unsigned short*)alloc((size_t)NBLK * PH * DCH * 2);
    unsigned short* convout = (unsigned short*)alloc((size_t)NBLK * 512 * DCH * 2);

    k_zero_pad<<<NBLK, 256, 0, stream>>>(P);
    k_w2t<<<384, 256, 0, stream>>>(conv_w, W2t);
    k_logits<<<NCHUNK, 256, 0, stream>>>(x, w_lw, b_lw, logits, cmax);
    k_seed_max<<<1, 64, 0, stream>>>(cmax, seedM);
    k_chunk_sums<<<NCHUNK, 256, 0, stream>>>(x, logits, seedM, exbuf, S_ex, S_exx);
    k_seed_sums<<<NB, 128, 0, stream>>>(S_ex, S_exx, seed_ex, seed_exx);
    k_apply<<<NCHUNK, 128, 0, stream>>>(x, exbuf, seed_ex, seed_exx, P);
    k_conv<<<NBLK * 4, 256, 0, stream>>>(P, W2t, conv_b, convout);
    k_as<<<NBLK, 256, 0, stream>>>(convout, block_repr, a_s);
    k_ao<<<NBLK, 128, 0, stream>>>(P, block_repr, a_o);
    k_fusion<<<NBLK, 128, 0, stream>>>(a_s, a_o, block_repr, fusion_w, fusion_b, out);
}

// Round 4
// 489.020 us; speedup vs baseline: 1.6931x; 1.2250x over previous
//
#include <hip/hip_runtime.h>
#include <hip/hip_bf16.h>

// Problem constants (reference: D=128, BC=64, BS=512, K=6, OV=128, B=8)
#define NB 8            // batches
#define LSEQ 32768      // BC*BS positions per batch
#define DCH 128         // channels
#define CS 256          // scan chunk size
#define NCHUNK 1024     // NB * LSEQ / CS
#define NBLK 512        // B*BC conv blocks
#define PH 520          // padded rows per block (2 front + 512 + pad, rounded)
#define SCALE_F 0.08838834764831845f

typedef __bf16 bf16x8 __attribute__((ext_vector_type(8)));
typedef float f32x4 __attribute__((ext_vector_type(4)));

__device__ __forceinline__ float bf2f(unsigned short u) {
    return __uint_as_float(((unsigned)u) << 16);
}
__device__ __forceinline__ unsigned short f2bf(float f) {
    unsigned u = __float_as_uint(f);
    u += 0x7fffu + ((u >> 16) & 1u);   // round-to-nearest-even
    return (unsigned short)(u >> 16);
}

// async global->LDS DMA, 16 B per lane; LDS dest = wave-uniform base + lane*16
__device__ __forceinline__ void async_copy16(const void* gsrc, void* ldst) {
    __builtin_amdgcn_global_load_lds(
        (const __attribute__((address_space(1))) unsigned int*)gsrc,
        (__attribute__((address_space(3))) unsigned int*)ldst, 16, 0, 0);
}

// ---------------- Stage 1: logits = silu(x @ w_lw + b) + per-chunk max ----------------
__global__ __launch_bounds__(256) void k_logits(const float* __restrict__ x,
                                                const float* __restrict__ w_lw,
                                                const float* __restrict__ b_lw,
                                                float* __restrict__ logits,
                                                float* __restrict__ cmax) {
    int chunk = blockIdx.x;
    int t = threadIdx.x, wave = t >> 6, lane = t & 63;
    __shared__ float wmax_lds[4];
    float2 wl = *(const float2*)(w_lw + 2 * lane);
    float bb = b_lw[0];
    float wmax = -INFINITY;
    int p0 = chunk * CS;
    for (int i = 0; i < 64; i++) {
        int pos = p0 + wave * 64 + i;
        float2 xv = *(const float2*)(x + (size_t)pos * DCH + 2 * lane);
        float d = xv.x * wl.x + xv.y * wl.y;
        #pragma unroll
        for (int off = 32; off >= 1; off >>= 1) d += __shfl_xor(d, off, 64);
        float z = d + bb;
        float lg = z / (1.f + expf(-z));
        if (lane == 0) logits[pos] = lg;
        wmax = fmaxf(wmax, lg);
    }
    if (lane == 0) wmax_lds[wave] = wmax;
    __syncthreads();
    if (t == 0)
        cmax[chunk] = fmaxf(fmaxf(wmax_lds[0], wmax_lds[1]), fmaxf(wmax_lds[2], wmax_lds[3]));
}

// ---------------- Stage 2: exclusive prefix-max of chunk maxima (per batch) ----------------
__global__ void k_seed_max(const float* __restrict__ cmax, float* __restrict__ seedM) {
    int b = threadIdx.x;
    if (b < NB) {
        float run = -INFINITY;
        for (int c = 0; c < 128; c++) {
            seedM[b * 128 + c] = run;
            run = fmaxf(run, cmax[b * 128 + c]);
        }
    }
}

// ---------------- Stage 3: in-chunk cummax -> ex; chunk sums of ex and ex*x ----------------
__global__ __launch_bounds__(256) void k_chunk_sums(const float* __restrict__ x,
                                                    const float* __restrict__ logits,
                                                    const float* __restrict__ seedM,
                                                    float* __restrict__ ex,
                                                    float* __restrict__ S_ex,
                                                    float* __restrict__ S_exx) {
    int chunk = blockIdx.x, t = threadIdx.x;
    __shared__ float sc[CS];
    __shared__ float exl[CS];
    __shared__ float red[256];
    int p0 = chunk * CS;
    float lv = logits[p0 + t];
    sc[t] = lv;
    __syncthreads();
    // Hillis-Steele inclusive max-scan over 256
    for (int off = 1; off < CS; off <<= 1) {
        float v = sc[t];
        if (t >= off) v = fmaxf(v, sc[t - off]);
        __syncthreads();
        sc[t] = v;
        __syncthreads();
    }
    float pmax = fmaxf(sc[t], seedM[chunk]);
    float e = expf(lv - pmax);
    exl[t] = e;
    ex[p0 + t] = e;
    red[t] = e;
    __syncthreads();
    for (int off = 128; off > 0; off >>= 1) {
        if (t < off) red[t] += red[t + off];
        __syncthreads();
    }
    if (t == 0) S_ex[chunk] = red[0];
    // sum over chunk of ex[j]*x[j][c]  (two halves per channel)
    int c = t & 127, half = t >> 7;
    float acc = 0.f;
    const float* xp = x + (size_t)(p0 + half * 128) * DCH + c;
    for (int j = 0; j < 128; j++) acc += exl[half * 128 + j] * xp[j * DCH];
    red[t] = acc;
    __syncthreads();
    if (t < 128) S_exx[chunk * DCH + t] = red[t] + red[t + 128];
}

// ---------------- Stage 4: exclusive prefix sums of chunk aggregates ----------------
__global__ __launch_bounds__(128) void k_seed_sums(const float* __restrict__ S_ex,
                                                   const float* __restrict__ S_exx,
                                                   float* __restrict__ seed_ex,
                                                   float* __restrict__ seed_exx) {
    int b = blockIdx.x, t = threadIdx.x;
    float accv = 0.f, accs = 0.f;
    for (int c = 0; c < 128; c++) {
        int ch = b * 128 + c;
        if (t == 0) seed_ex[ch] = accs;
        accs += S_ex[ch];
        seed_exx[ch * DCH + t] = accv;
        accv += S_exx[ch * DCH + t];
    }
}

// ---------------- zero the halo rows of P ----------------
__global__ __launch_bounds__(256) void k_zero_pad(unsigned short* __restrict__ P) {
    int n = blockIdx.x, t = threadIdx.x;
    for (int i = t; i < 1024; i += 256) {
        int rr = i >> 7;                       // 0..7
        int row = (rr < 2) ? rr : 512 + rr;    // rows 0,1,514..519
        P[(n * PH + row) * DCH + (i & 127)] = 0;
    }
}

// ---------------- Stage 5: apply scan -> prefix_x, write bf16 padded P ----------------
__global__ __launch_bounds__(128) void k_apply(const float* __restrict__ x,
                                               const float* __restrict__ ex,
                                               const float* __restrict__ seed_ex,
                                               const float* __restrict__ seed_exx,
                                               unsigned short* __restrict__ P) {
    int chunk = blockIdx.x, t = threadIdx.x;   // 128 threads
    int b = chunk >> 7, cb = chunk & 127;
    __shared__ float exl[CS];
    exl[t] = ex[chunk * CS + t];
    exl[t + 128] = ex[chunk * CS + 128 + t];
    __syncthreads();
    float acc_exx = seed_exx[chunk * DCH + t];
    float acc_ex = seed_ex[chunk];
    int pib0 = cb * CS;
    for (int j = 0; j < CS; j++) {
        int pos = chunk * CS + j;
        float e = exl[j];
        acc_ex += e;
        float xv = x[(size_t)pos * DCH + t];
        acc_exx += e * xv;
        float val = acc_exx / acc_ex + xv;
        int pib = pib0 + j;
        int n = b * 64 + (pib >> 9);
        int row = (pib & 511) + 2;
        P[(n * PH + row) * DCH + t] = f2bf(val);
    }
}

// ---------------- weight repack: W2t[o][kn*128+i] = conv_w[o][i][kn], bf16 ----------------
__global__ __launch_bounds__(256) void k_w2t(const float* __restrict__ conv_w,
                                             unsigned short* __restrict__ W2t) {
    int idx = blockIdx.x * 256 + threadIdx.x;  // 128*768 = 98304
    if (idx < 128 * 768) {
        int o = idx / 768, kk = idx % 768;
        int kn = kk >> 7, i = kk & 127;
        W2t[idx] = f2bf(conv_w[(o * 128 + i) * 6 + kn]);
    }
}

// ---------------- Stage 6: conv as bf16 MFMA GEMM (128x128 tile, K=768) ----------------
// global_load_lds DMA staging, XOR-swizzled at the DMA *source* so the unpadded
// LDS image reads conflict-free. LDS: A[128][64] @0, B[128][64] @16KB (ushort),
// epilogue C-stage reuses the whole buffer at stride 136.
__global__ __launch_bounds__(256) void k_conv(const unsigned short* __restrict__ P,
                                              const unsigned short* __restrict__ W2t,
                                              const float* __restrict__ conv_b,
                                              unsigned short* __restrict__ convout) {
    int n = blockIdx.x >> 2;
    int h0 = (blockIdx.x & 3) * 128;
    __shared__ __align__(16) unsigned short lds[128 * 136];  // 34,816 B (>= 32 KB A+B)
    char* ldsA = (char*)lds;
    char* ldsB = (char*)lds + 16384;
    int t = threadIdx.x;
    int wave = t >> 6, lane = t & 63;
    f32x4 acc[4][4] = {};
    const unsigned short* Pn = P + (size_t)n * PH * DCH;
    int wm = (wave >> 1) * 64, wn = (wave & 1) * 64;
    int rdma = (lane >> 3);        // row-within-8 handled per DMA instr
    int cpos = lane & 7;           // LDS chunk position this lane fills

    for (int kt = 0; kt < 12; ++kt) {
        int kn = kt >> 1;              // neighbor offset 0..5
        int c0 = (kt & 1) * 64;        // channel slice 0 or 64
        __syncthreads();   // all waves done reading LDS for kt-1
        #pragma unroll
        for (int j = 0; j < 4; ++j) {
            int r = (wave * 4 + j) * 8 + rdma;          // LDS row 0..127
            int gr = h0 + kn + r;                       // global padded row
            int csrcA = cpos ^ (gr & 7);                // source-side swizzle
            async_copy16(Pn + (size_t)gr * DCH + c0 + csrcA * 8,
                         ldsA + (wave * 4 + j) * 1024 + lane * 16);
            int csrcB = cpos ^ (r & 7);
            async_copy16(W2t + (size_t)r * 768 + kt * 64 + csrcB * 8,
                         ldsB + (wave * 4 + j) * 1024 + lane * 16);
        }
        __syncthreads();   // drains vmcnt(0): DMA complete
        #pragma unroll
        for (int ks = 0; ks < 2; ++ks) {
            bf16x8 af[4], bfr[4];
            #pragma unroll
            for (int mi = 0; mi < 4; ++mi) {
                int rA = wm + mi * 16 + (lane & 15);
                int pA = (ks * 4 + (lane >> 4)) ^ ((kn + rA) & 7);
                af[mi] = *(const bf16x8*)(ldsA + rA * 128 + pA * 16);
            }
            #pragma unroll
            for (int ni = 0; ni < 4; ++ni) {
                int oB = wn + ni * 16 + (lane & 15);
                int pB = (ks * 4 + (lane >> 4)) ^ (oB & 7);
                bfr[ni] = *(const bf16x8*)(ldsB + oB * 128 + pB * 16);
            }
            #pragma unroll
            for (int mi = 0; mi < 4; ++mi)
                #pragma unroll
                for (int ni = 0; ni < 4; ++ni)
                    acc[mi][ni] = __builtin_amdgcn_mfma_f32_16x16x32_bf16(af[mi], bfr[ni],
                                                                          acc[mi][ni], 0, 0, 0);
        }
    }
    __syncthreads();   // all A/B LDS reads complete before C-stage overwrite
    // C/D layout: col=lane&15, row=(lane>>4)*4+reg  [m89-verified]
    #pragma unroll
    for (int mi = 0; mi < 4; ++mi)
        #pragma unroll
        for (int ni = 0; ni < 4; ++ni) {
            int col = wn + ni * 16 + (lane & 15);
            float bias = conv_b[col];
            #pragma unroll
            for (int r = 0; r < 4; ++r) {
                int row = wm + mi * 16 + (lane >> 4) * 4 + r;
                lds[row * 136 + col] = f2bf(acc[mi][ni][r] + bias);
            }
        }
    __syncthreads();
    // coalesced store: 2048 granules of 16 B
    size_t base = (size_t)(n * 512 + h0) * DCH;
    #pragma unroll
    for (int it = 0; it < 8; ++it) {
        int idx = it * 256 + t;
        int row = idx >> 4, g = idx & 15;
        uint4 v = *(const uint4*)(lds + row * 136 + g * 8);
        *(uint4*)(convout + base + (size_t)row * DCH + g * 8) = v;
    }
}

// ---------------- Stage 7+8 fused: block_repr + a_s, column-parallel uint4 passes ----------------
// thread t: granule g=t&15 (channels 8g..8g+7), row-slice rs=t>>4; every global
// load is a coalesced 16B; per-row dot products reduced via padded LDS partials
// (no per-row shuffle trees).
__global__ __launch_bounds__(256) void k_as(const unsigned short* __restrict__ conv,
                                            float* __restrict__ block_repr,
                                            float* __restrict__ a_s) {
    int n = blockIdx.x, t = threadIdx.x;
    int g = t & 15, rs = t >> 4;
    __shared__ __align__(16) float sp[512 * 17];   // row-partials / rp[16][130] / red scratch
    __shared__ float s[512];
    __shared__ float br[128];
    float* rp = sp;                                 // [16][130] view
    const unsigned short* base = conv + (size_t)n * 512 * DCH;

    // ---- phase 0: column max ----
    float m[8];
    #pragma unroll
    for (int e = 0; e < 8; ++e) m[e] = -INFINITY;
    for (int i = 0; i < 32; ++i) {
        int row = i * 16 + rs;
        uint4 v = *(const uint4*)(base + row * DCH + g * 8);
        unsigned vv[4] = {v.x, v.y, v.z, v.w};
        #pragma unroll
        for (int e = 0; e < 4; ++e) {
            m[2 * e]     = fmaxf(m[2 * e],     bf2f((unsigned short)(vv[e] & 0xffff)));
            m[2 * e + 1] = fmaxf(m[2 * e + 1], bf2f((unsigned short)(vv[e] >> 16)));
        }
    }
    #pragma unroll
    for (int e = 0; e < 8; ++e) rp[rs * 130 + g * 8 + e] = m[e];
    __syncthreads();
    if (t < 128) {
        float bm = rp[t];
        #pragma unroll
        for (int r2 = 1; r2 < 16; ++r2) bm = fmaxf(bm, rp[r2 * 130 + t]);
        br[t] = bm;
        block_repr[n * DCH + t] = bm;
    }
    __syncthreads();

    // ---- phase 1: scores s[row] = (conv[row] . br) * SCALE ----
    float brv[8];
    #pragma unroll
    for (int e = 0; e < 8; ++e) brv[e] = br[g * 8 + e];
    for (int i = 0; i < 32; ++i) {
        int row = i * 16 + rs;
        uint4 v = *(const uint4*)(base + row * DCH + g * 8);
        unsigned vv[4] = {v.x, v.y, v.z, v.w};
        float p = 0.f;
        #pragma unroll
        for (int e = 0; e < 4; ++e) {
            p += bf2f((unsigned short)(vv[e] & 0xffff)) * brv[2 * e];
            p += bf2f((unsigned short)(vv[e] >> 16))    * brv[2 * e + 1];
        }
        sp[row * 17 + g] = p;
    }
    __syncthreads();
    #pragma unroll
    for (int rr = 0; rr < 2; ++rr) {
        int row = t * 2 + rr;
        float p = 0.f;
        #pragma unroll
        for (int j = 0; j < 16; ++j) p += sp[row * 17 + j];
        s[row] = p * SCALE_F;
    }
    __syncthreads();

    // ---- softmax over s[512] (scratch reuses sp after scores consumed) ----
    float* red = sp;
    float mm = fmaxf(s[t], s[t + 256]);
    __syncthreads();          // all score reads of sp done before overwrite
    red[t] = mm;
    __syncthreads();
    for (int off = 128; off > 0; off >>= 1) {
        if (t < off) red[t] = fmaxf(red[t], red[t + off]);
        __syncthreads();
    }
    float smax = red[0];
    __syncthreads();
    float e0 = expf(s[t] - smax), e1 = expf(s[t + 256] - smax);
    red[t] = e0 + e1;
    __syncthreads();
    for (int off = 128; off > 0; off >>= 1) {
        if (t < off) red[t] += red[t + off];
        __syncthreads();
    }
    float inv = 1.f / red[0];
    __syncthreads();
    s[t] = e0 * inv;
    s[t + 256] = e1 * inv;
    __syncthreads();

    // ---- phase 2: weighted sum ----
    float acc[8];
    #pragma unroll
    for (int e = 0; e < 8; ++e) acc[e] = 0.f;
    for (int i = 0; i < 32; ++i) {
        int row = i * 16 + rs;
        float w = s[row];
        uint4 v = *(const uint4*)(base + row * DCH + g * 8);
        unsigned vv[4] = {v.x, v.y, v.z, v.w};
        #pragma unroll
        for (int e = 0; e < 4; ++e) {
            acc[2 * e]     += w * bf2f((unsigned short)(vv[e] & 0xffff));
            acc[2 * e + 1] += w * bf2f((unsigned short)(vv[e] >> 16));
        }
    }
    #pragma unroll
    for (int e = 0; e < 8; ++e) rp[rs * 130 + g * 8 + e] = acc[e];
    __syncthreads();
    if (t < 128) {
        float p = 0.f;
        #pragma unroll
        for (int r2 = 0; r2 < 16; ++r2) p += rp[r2 * 130 + t];
        a_s[n * DCH + t] = p;
    }
}

// ---------------- Stage 9: a_o = attn(block_repr, xbo, xbo) over OV=128 window ----------------
__global__ __launch_bounds__(128) void k_ao(const unsigned short* __restrict__ P,
                                            const float* __restrict__ block_repr,
                                            float* __restrict__ a_o) {
    int n = blockIdx.x, t = threadIdx.x, wave = t >> 6, lane = t & 63;
    int b = n >> 6, c = n & 63;
    __shared__ float br[128];
    __shared__ float s[128];
    __shared__ int rb[128];
    __shared__ float red[128];
    br[t] = block_repr[n * DCH + t];
    {
        int pib = (c + 1) * 512 - 64 + t;       // window straddling block end
        pib = min(pib, LSEQ - 1);               // edge-clamp at sequence end
        int n2 = b * 64 + (pib >> 9);
        int row = (pib & 511) + 2;
        rb[t] = (n2 * PH + row) * DCH;
    }
    __syncthreads();
    float b0 = br[2 * lane], b1 = br[2 * lane + 1];
    for (int i = 0; i < 64; i++) {
        int q = wave * 64 + i;
        unsigned v = *(const unsigned*)(P + rb[q] + 2 * lane);
        float d = bf2f(v & 0xffff) * b0 + bf2f(v >> 16) * b1;
        #pragma unroll
        for (int off = 32; off >= 1; off >>= 1) d += __shfl_xor(d, off, 64);
        if (lane == 0) s[q] = d * SCALE_F;
    }
    __syncthreads();
    red[t] = s[t];
    __syncthreads();
    for (int off = 64; off > 0; off >>= 1) {
        if (t < off) red[t] = fmaxf(red[t], red[t + off]);
        __syncthreads();
    }
    float smax = red[0];
    __syncthreads();
    float e = expf(s[t] - smax);
    red[t] = e;
    __syncthreads();
    for (int off = 64; off > 0; off >>= 1) {
        if (t < off) red[t] += red[t + off];
        __syncthreads();
    }
    float inv = 1.f / red[0];
    __syncthreads();
    s[t] = e * inv;
    __syncthreads();
    float acc = 0.f;
    for (int q = 0; q < 128; q++) acc += s[q] * bf2f(P[rb[q] + t]);
    a_o[n * DCH + t] = acc;
}

// ---------------- Stage 10: out = concat(a_s,a_o,br) @ fusion_w + fusion_b (x2 copies) ----------------
__global__ __launch_bounds__(128) void k_fusion(const float* __restrict__ a_s,
                                                const float* __restrict__ a_o,
                                                const float* __restrict__ block_repr,
                                                const float* __restrict__ fusion_w,
                                                const float* __restrict__ fusion_b,
                                                float* __restrict__ out) {
    int n = blockIdx.x, t = threadIdx.x;
    __shared__ float fu[384];
    fu[t] = a_s[n * DCH + t];
    fu[128 + t] = a_o[n * DCH + t];
    fu[256 + t] = block_repr[n * DCH + t];
    __syncthreads();
    float acc = fusion_b[t];
    for (int j = 0; j < 384; j++) acc += fu[j] * fusion_w[j * DCH + t];
    out[n * DCH + t] = acc;
    out[NB * 64 * DCH + n * DCH + t] = acc;   // second tuple element (out, out)
}

extern "C" void kernel_launch(void* const* d_in, const int* in_sizes, int n_in,
                              void* d_out, int out_size, void* d_ws, size_t ws_size,
                              hipStream_t stream) {
    const float* x        = (const float*)d_in[0];
    const float* w_lw     = (const float*)d_in[1];
    const float* b_lw     = (const float*)d_in[2];
    const float* conv_w   = (const float*)d_in[3];
    const float* conv_b   = (const float*)d_in[4];
    const float* fusion_w = (const float*)d_in[5];
    const float* fusion_b = (const float*)d_in[6];
    float* out = (float*)d_out;

    char* ws = (char*)d_ws;
    size_t off = 0;
    auto alloc = [&](size_t bytes) { char* p = ws + off; off += (bytes + 255) & ~(size_t)255; return p; };
    float* logits     = (float*)alloc(NB * LSEQ * 4);
    float* exbuf      = (float*)alloc(NB * LSEQ * 4);
    float* cmax       = (float*)alloc(NCHUNK * 4);
    float* seedM      = (float*)alloc(NCHUNK * 4);
    float* S_ex       = (float*)alloc(NCHUNK * 4);
    float* seed_ex    = (float*)alloc(NCHUNK * 4);
    float* S_exx      = (float*)alloc(NCHUNK * DCH * 4);
    float* seed_exx   = (float*)alloc(NCHUNK * DCH * 4);
    float* block_repr = (float*)alloc(NBLK * DCH * 4);
    float* a_s        = (float*)alloc(NBLK * DCH * 4);
    float* a_o        = (float*)alloc(NBLK * DCH * 4);
    unsigned short* W2t     = (unsigned short*)alloc(128 * 768 * 2);
    unsigned short* P       = (unsigned short*)alloc((size_t)NBLK * PH * DCH * 2);
    unsigned short* convout = (unsigned short*)alloc((size_t)NBLK * 512 * DCH * 2);

    k_zero_pad<<<NBLK, 256, 0, stream>>>(P);
    k_w2t<<<384, 256, 0, stream>>>(conv_w, W2t);
    k_logits<<<NCHUNK, 256, 0, stream>>>(x, w_lw, b_lw, logits, cmax);
    k_seed_max<<<1, 64, 0, stream>>>(cmax, seedM);
    k_chunk_sums<<<NCHUNK, 256, 0, stream>>>(x, logits, seedM, exbuf, S_ex, S_exx);
    k_seed_sums<<<NB, 128, 0, stream>>>(S_ex, S_exx, seed_ex, seed_exx);
    k_apply<<<NCHUNK, 128, 0, stream>>>(x, exbuf, seed_ex, seed_exx, P);
    k_conv<<<NBLK * 4, 256, 0, stream>>>(P, W2t, conv_b, convout);
    k_as<<<NBLK, 256, 0, stream>>>(convout, block_repr, a_s);
    k_ao<<<NBLK, 128, 0, stream>>>(P, block_repr, a_o);
    k_fusion<<<NBLK, 128, 0, stream>>>(a_s, a_o, block_repr, fusion_w, fusion_b, out);
}